// Round 1
// baseline (1292.537 us; speedup 1.0000x reference)
//
#include <hip/hip_runtime.h>

#define CN 128
#define NB 16
#define KS 7
#define PD 3
#define HW 224
#define TILE_H 32
#define ROWS_IN 38      // TILE_H + 6
#define LSTR 232        // 4 pad + 224 + 4 pad, floats
#define NTH 448         // 7 waves
#define NXG 56          // 224/4 float4 groups per row
#define RPT 4           // output rows per thread
#define YTILES 7        // 224/32

__device__ __forceinline__ float wget(const float* kv, int p) {
    // symmetric 7x7: flat position p and 48-p share parameter min(p,48-p)
    return kv[(p < 25) ? p : 48 - p];
}

__global__ __launch_bounds__(NTH, 7)
void dwconv7x7_sym(const float* __restrict__ x, const float* __restrict__ kv,
                   float* __restrict__ out) {
    __shared__ float lds[ROWS_IN * LSTR];
    const int bid   = blockIdx.x;
    const int plane = bid / YTILES;
    const int ytile = bid - plane * YTILES;
    const int y0    = ytile * TILE_H;
    const float* xp = x + (size_t)plane * (HW * HW);
    float* op       = out + (size_t)plane * (HW * HW);
    const int tid = threadIdx.x;

    // zero the left/right 4-float pads of every staged row
    for (int s = tid; s < ROWS_IN * 2; s += NTH) {
        int r = s >> 1;
        int side = s & 1;
        float4 z = make_float4(0.f, 0.f, 0.f, 0.f);
        *reinterpret_cast<float4*>(&lds[r * LSTR + side * 228]) = z;
    }
    // stage 38 rows (vertical zero padding via row guard); columns always in range
    for (int s = tid; s < ROWS_IN * NXG; s += NTH) {
        int r  = s / NXG;
        int c4 = s - r * NXG;
        int gr = y0 - PD + r;
        float4 v = make_float4(0.f, 0.f, 0.f, 0.f);
        if (gr >= 0 && gr < HW)
            v = *reinterpret_cast<const float4*>(xp + gr * HW + c4 * 4);
        *reinterpret_cast<float4*>(&lds[r * LSTR + 4 + c4 * 4]) = v;
    }
    __syncthreads();

    const int xg = tid % NXG;          // 0..55
    const int yt = tid / NXG;          // 0..7
    const int x0 = xg * 4;

    float acc[RPT][4];
    #pragma unroll
    for (int q = 0; q < RPT; ++q)
        #pragma unroll
        for (int c = 0; c < 4; ++c) acc[q][c] = 0.f;

    // loop over the 10 input rows this thread's 4 output rows need
    #pragma unroll
    for (int j = 0; j < RPT + KS - 1; ++j) {
        const float* rp = &lds[(yt * RPT + j) * LSTR + x0];  // holds cols x0-4 .. x0+7
        float rv[12];
        float4 a   = *reinterpret_cast<const float4*>(rp);
        float4 b   = *reinterpret_cast<const float4*>(rp + 4);
        float4 c4v = *reinterpret_cast<const float4*>(rp + 8);
        rv[0]=a.x;  rv[1]=a.y;  rv[2]=a.z;  rv[3]=a.w;
        rv[4]=b.x;  rv[5]=b.y;  rv[6]=b.z;  rv[7]=b.w;
        rv[8]=c4v.x;rv[9]=c4v.y;rv[10]=c4v.z;rv[11]=c4v.w;
        #pragma unroll
        for (int q = 0; q < RPT; ++q) {
            const int wr = j - q;               // weight row (dy+3)
            if (wr >= 0 && wr < KS) {
                #pragma unroll
                for (int dx = 0; dx < KS; ++dx) {
                    const float wgt = wget(kv, wr * KS + dx);
                    #pragma unroll
                    for (int c = 0; c < 4; ++c)
                        // output col x0+c needs input col x0+c+dx-3 -> rv[c+dx+1]
                        acc[q][c] = fmaf(wgt, rv[dx + c + 1], acc[q][c]);
                }
            }
        }
    }

    const int orow0 = y0 + yt * RPT;
    #pragma unroll
    for (int q = 0; q < RPT; ++q) {
        float4 v = make_float4(acc[q][0], acc[q][1], acc[q][2], acc[q][3]);
        *reinterpret_cast<float4*>(op + (orow0 + q) * HW + x0) = v;
    }
}

extern "C" void kernel_launch(void* const* d_in, const int* in_sizes, int n_in,
                              void* d_out, int out_size, void* d_ws, size_t ws_size,
                              hipStream_t stream) {
    const float* x  = (const float*)d_in[0];   // (16,128,224,224) f32
    const float* kv = (const float*)d_in[1];   // (25,) f32
    float* out = (float*)d_out;
    dim3 grid(NB * CN * YTILES);               // 14336 blocks
    dwconv7x7_sym<<<grid, NTH, 0, stream>>>(x, kv, out);
}

// Round 2
// 402.995 us; speedup vs baseline: 3.2073x; 3.2073x over previous
//
#include <hip/hip_runtime.h>

#define CN 128
#define NB 16
#define KS 7
#define PD 3
#define HW 224
#define TILE_H 32
#define ROWS_IN 38      // TILE_H + 6
#define LSTR 232        // 4 pad + 224 + 4 pad, floats
#define NTH 448         // 7 waves
#define NXG 56          // 224/4 float4 groups per row
#define RPT 4           // output rows per thread
#define YTILES 7        // 224/32

// symmetric 7x7: flat position P and 48-P share parameter min(P,48-P).
// P is always a compile-time constant -> folds to a constant index into wv.
#define W(P) wv[((P) < 25) ? (P) : (48 - (P))]

// FMAs for output row Q using weight row WR (both compile-time constants).
// Window regs r1..r10 hold input cols x0-3 .. x0+6 of the current input row.
#define FMA_QROW(Q, WR) \
  acx##Q = fmaf(W((WR)*7+0), r1,  acx##Q); \
  acx##Q = fmaf(W((WR)*7+1), r2,  acx##Q); \
  acx##Q = fmaf(W((WR)*7+2), r3,  acx##Q); \
  acx##Q = fmaf(W((WR)*7+3), r4,  acx##Q); \
  acx##Q = fmaf(W((WR)*7+4), r5,  acx##Q); \
  acx##Q = fmaf(W((WR)*7+5), r6,  acx##Q); \
  acx##Q = fmaf(W((WR)*7+6), r7,  acx##Q); \
  acy##Q = fmaf(W((WR)*7+0), r2,  acy##Q); \
  acy##Q = fmaf(W((WR)*7+1), r3,  acy##Q); \
  acy##Q = fmaf(W((WR)*7+2), r4,  acy##Q); \
  acy##Q = fmaf(W((WR)*7+3), r5,  acy##Q); \
  acy##Q = fmaf(W((WR)*7+4), r6,  acy##Q); \
  acy##Q = fmaf(W((WR)*7+5), r7,  acy##Q); \
  acy##Q = fmaf(W((WR)*7+6), r8,  acy##Q); \
  acz##Q = fmaf(W((WR)*7+0), r3,  acz##Q); \
  acz##Q = fmaf(W((WR)*7+1), r4,  acz##Q); \
  acz##Q = fmaf(W((WR)*7+2), r5,  acz##Q); \
  acz##Q = fmaf(W((WR)*7+3), r6,  acz##Q); \
  acz##Q = fmaf(W((WR)*7+4), r7,  acz##Q); \
  acz##Q = fmaf(W((WR)*7+5), r8,  acz##Q); \
  acz##Q = fmaf(W((WR)*7+6), r9,  acz##Q); \
  acw##Q = fmaf(W((WR)*7+0), r4,  acw##Q); \
  acw##Q = fmaf(W((WR)*7+1), r5,  acw##Q); \
  acw##Q = fmaf(W((WR)*7+2), r6,  acw##Q); \
  acw##Q = fmaf(W((WR)*7+3), r7,  acw##Q); \
  acw##Q = fmaf(W((WR)*7+4), r8,  acw##Q); \
  acw##Q = fmaf(W((WR)*7+5), r9,  acw##Q); \
  acw##Q = fmaf(W((WR)*7+6), r10, acw##Q);

// Load input row J (thread-local) of the LDS tile into named window regs.
#define LOAD_ROW(J) \
  { const float4 A_  = *reinterpret_cast<const float4*>(lrow + (J)*LSTR); \
    const float4 B_  = *reinterpret_cast<const float4*>(lrow + (J)*LSTR + 4); \
    const float4 C_  = *reinterpret_cast<const float4*>(lrow + (J)*LSTR + 8); \
    r1=A_.y; r2=A_.z; r3=A_.w; r4=B_.x; r5=B_.y; r6=B_.z; r7=B_.w; \
    r8=C_.x; r9=C_.y; r10=C_.z; }

__global__ __launch_bounds__(NTH, 7)
void dwconv7x7_sym(const float* __restrict__ x, const float* __restrict__ kv,
                   float* __restrict__ out) {
    __shared__ float lds[ROWS_IN * LSTR];
    const int bid   = blockIdx.x;
    const int plane = bid / YTILES;
    const int ytile = bid - plane * YTILES;
    const int y0    = ytile * TILE_H;
    const float* xp = x + (size_t)plane * (HW * HW);
    float* op       = out + (size_t)plane * (HW * HW);
    const int tid = threadIdx.x;

    // uniform weights -> scalar loads (SGPRs); all later indices are literals
    float wv[25];
    #pragma unroll
    for (int i = 0; i < 25; ++i) wv[i] = kv[i];

    // zero the left/right 4-float pads of every staged row
    for (int s = tid; s < ROWS_IN * 2; s += NTH) {
        int r = s >> 1;
        int side = s & 1;
        float4 z = make_float4(0.f, 0.f, 0.f, 0.f);
        *reinterpret_cast<float4*>(&lds[r * LSTR + side * 228]) = z;
    }
    // stage 38 rows (vertical zero padding via row guard)
    for (int s = tid; s < ROWS_IN * NXG; s += NTH) {
        int r  = s / NXG;
        int c4 = s - r * NXG;
        int gr = y0 - PD + r;
        float4 v = make_float4(0.f, 0.f, 0.f, 0.f);
        if (gr >= 0 && gr < HW)
            v = *reinterpret_cast<const float4*>(xp + gr * HW + c4 * 4);
        *reinterpret_cast<float4*>(&lds[r * LSTR + 4 + c4 * 4]) = v;
    }
    __syncthreads();

    const int xg = tid % NXG;          // 0..55
    const int yt = tid / NXG;          // 0..7
    const int x0 = xg * 4;
    const float* lrow = &lds[yt * RPT * LSTR + x0];

    float acx0=0.f, acy0=0.f, acz0=0.f, acw0=0.f;
    float acx1=0.f, acy1=0.f, acz1=0.f, acw1=0.f;
    float acx2=0.f, acy2=0.f, acz2=0.f, acw2=0.f;
    float acx3=0.f, acy3=0.f, acz3=0.f, acw3=0.f;
    float r1,r2,r3,r4,r5,r6,r7,r8,r9,r10;

    LOAD_ROW(0); FMA_QROW(0,0);
    LOAD_ROW(1); FMA_QROW(0,1); FMA_QROW(1,0);
    LOAD_ROW(2); FMA_QROW(0,2); FMA_QROW(1,1); FMA_QROW(2,0);
    LOAD_ROW(3); FMA_QROW(0,3); FMA_QROW(1,2); FMA_QROW(2,1); FMA_QROW(3,0);
    LOAD_ROW(4); FMA_QROW(0,4); FMA_QROW(1,3); FMA_QROW(2,2); FMA_QROW(3,1);
    LOAD_ROW(5); FMA_QROW(0,5); FMA_QROW(1,4); FMA_QROW(2,3); FMA_QROW(3,2);
    LOAD_ROW(6); FMA_QROW(0,6); FMA_QROW(1,5); FMA_QROW(2,4); FMA_QROW(3,3);
    LOAD_ROW(7);                FMA_QROW(1,6); FMA_QROW(2,5); FMA_QROW(3,4);
    LOAD_ROW(8);                               FMA_QROW(2,6); FMA_QROW(3,5);
    LOAD_ROW(9);                                              FMA_QROW(3,6);

    const int orow0 = y0 + yt * RPT;
    *reinterpret_cast<float4*>(op + (orow0 + 0) * HW + x0) = make_float4(acx0, acy0, acz0, acw0);
    *reinterpret_cast<float4*>(op + (orow0 + 1) * HW + x0) = make_float4(acx1, acy1, acz1, acw1);
    *reinterpret_cast<float4*>(op + (orow0 + 2) * HW + x0) = make_float4(acx2, acy2, acz2, acw2);
    *reinterpret_cast<float4*>(op + (orow0 + 3) * HW + x0) = make_float4(acx3, acy3, acz3, acw3);
}

extern "C" void kernel_launch(void* const* d_in, const int* in_sizes, int n_in,
                              void* d_out, int out_size, void* d_ws, size_t ws_size,
                              hipStream_t stream) {
    const float* x  = (const float*)d_in[0];   // (16,128,224,224) f32
    const float* kv = (const float*)d_in[1];   // (25,) f32
    float* out = (float*)d_out;
    dim3 grid(NB * CN * YTILES);               // 14336 blocks
    dwconv7x7_sym<<<grid, NTH, 0, stream>>>(x, kv, out);
}

// Round 3
// 401.031 us; speedup vs baseline: 3.2230x; 1.0049x over previous
//
#include <hip/hip_runtime.h>

#define CN 128
#define NB 16
#define KS 7
#define PD 3
#define HW 224
#define TILE_H 32
#define ROWS_IN 38      // TILE_H + 6
#define LSTR 232        // 4 pad + 224 + 4 pad, floats
#define NTH 448         // 7 waves
#define NXG 56          // 224/4 float4 groups per row
#define RPT 4           // output rows per thread
#define YTILES 7        // 224/32

// Load weight i into a NAMED scalar pinned to an SGPR (wave-uniform).
#define LW(i) const float w##i = __uint_as_float(__builtin_amdgcn_readfirstlane(__float_as_uint(kv[i])));

// FMAs for output row Q with explicit weight scalars (no arrays anywhere).
// Window regs r1..r10 hold input cols x0-3 .. x0+6 of the current input row.
#define FMA_QROW(Q, W0,W1,W2,W3,W4,W5,W6) \
  acx##Q = fmaf(W0, r1,  acx##Q); \
  acx##Q = fmaf(W1, r2,  acx##Q); \
  acx##Q = fmaf(W2, r3,  acx##Q); \
  acx##Q = fmaf(W3, r4,  acx##Q); \
  acx##Q = fmaf(W4, r5,  acx##Q); \
  acx##Q = fmaf(W5, r6,  acx##Q); \
  acx##Q = fmaf(W6, r7,  acx##Q); \
  acy##Q = fmaf(W0, r2,  acy##Q); \
  acy##Q = fmaf(W1, r3,  acy##Q); \
  acy##Q = fmaf(W2, r4,  acy##Q); \
  acy##Q = fmaf(W3, r5,  acy##Q); \
  acy##Q = fmaf(W4, r6,  acy##Q); \
  acy##Q = fmaf(W5, r7,  acy##Q); \
  acy##Q = fmaf(W6, r8,  acy##Q); \
  acz##Q = fmaf(W0, r3,  acz##Q); \
  acz##Q = fmaf(W1, r4,  acz##Q); \
  acz##Q = fmaf(W2, r5,  acz##Q); \
  acz##Q = fmaf(W3, r6,  acz##Q); \
  acz##Q = fmaf(W4, r7,  acz##Q); \
  acz##Q = fmaf(W5, r8,  acz##Q); \
  acz##Q = fmaf(W6, r9,  acz##Q); \
  acw##Q = fmaf(W0, r4,  acw##Q); \
  acw##Q = fmaf(W1, r5,  acw##Q); \
  acw##Q = fmaf(W2, r6,  acw##Q); \
  acw##Q = fmaf(W3, r7,  acw##Q); \
  acw##Q = fmaf(W4, r8,  acw##Q); \
  acw##Q = fmaf(W5, r9,  acw##Q); \
  acw##Q = fmaf(W6, r10, acw##Q);

// Weight rows of the symmetric 7x7 (flat p maps to param min(p,48-p)):
//   input row 0: w0..w6        input row 4: w20..w14 (reversed)
//   input row 1: w7..w13       input row 5: w13..w7  (reversed)
//   input row 2: w14..w20      input row 6: w6..w0   (reversed)
//   input row 3: w21 w22 w23 w24 w23 w22 w21 (palindrome)
#define QROW0(Q) FMA_QROW(Q, w0,w1,w2,w3,w4,w5,w6)
#define QROW1(Q) FMA_QROW(Q, w7,w8,w9,w10,w11,w12,w13)
#define QROW2(Q) FMA_QROW(Q, w14,w15,w16,w17,w18,w19,w20)
#define QROW3(Q) FMA_QROW(Q, w21,w22,w23,w24,w23,w22,w21)
#define QROW4(Q) FMA_QROW(Q, w20,w19,w18,w17,w16,w15,w14)
#define QROW5(Q) FMA_QROW(Q, w13,w12,w11,w10,w9,w8,w7)
#define QROW6(Q) FMA_QROW(Q, w6,w5,w4,w3,w2,w1,w0)

// Load input row J (thread-local) of the LDS tile into named window regs.
#define LOAD_ROW(J) \
  { const float4 A_  = *reinterpret_cast<const float4*>(lrow + (J)*LSTR); \
    const float4 B_  = *reinterpret_cast<const float4*>(lrow + (J)*LSTR + 4); \
    const float4 C_  = *reinterpret_cast<const float4*>(lrow + (J)*LSTR + 8); \
    r1=A_.y; r2=A_.z; r3=A_.w; r4=B_.x; r5=B_.y; r6=B_.z; r7=B_.w; \
    r8=C_.x; r9=C_.y; r10=C_.z; }

__global__ __launch_bounds__(NTH, 7)
void dwconv7x7_sym(const float* __restrict__ x, const float* __restrict__ kv,
                   float* __restrict__ out) {
    __shared__ float lds[ROWS_IN * LSTR];
    const int bid   = blockIdx.x;
    const int plane = bid / YTILES;
    const int ytile = bid - plane * YTILES;
    const int y0    = ytile * TILE_H;
    const float* xp = x + (size_t)plane * (HW * HW);
    float* op       = out + (size_t)plane * (HW * HW);
    const int tid = threadIdx.x;

    // 25 named weight scalars, pinned to SGPRs (wave-uniform)
    LW(0)  LW(1)  LW(2)  LW(3)  LW(4)  LW(5)  LW(6)  LW(7)  LW(8)  LW(9)
    LW(10) LW(11) LW(12) LW(13) LW(14) LW(15) LW(16) LW(17) LW(18) LW(19)
    LW(20) LW(21) LW(22) LW(23) LW(24)

    // zero the left/right 4-float pads of every staged row
    for (int s = tid; s < ROWS_IN * 2; s += NTH) {
        int r = s >> 1;
        int side = s & 1;
        float4 z = make_float4(0.f, 0.f, 0.f, 0.f);
        *reinterpret_cast<float4*>(&lds[r * LSTR + side * 228]) = z;
    }
    // stage 38 rows (vertical zero padding via row guard)
    for (int s = tid; s < ROWS_IN * NXG; s += NTH) {
        int r  = s / NXG;
        int c4 = s - r * NXG;
        int gr = y0 - PD + r;
        float4 v = make_float4(0.f, 0.f, 0.f, 0.f);
        if (gr >= 0 && gr < HW)
            v = *reinterpret_cast<const float4*>(xp + gr * HW + c4 * 4);
        *reinterpret_cast<float4*>(&lds[r * LSTR + 4 + c4 * 4]) = v;
    }
    __syncthreads();

    const int xg = tid % NXG;          // 0..55
    const int yt = tid / NXG;          // 0..7
    const int x0 = xg * 4;
    const float* lrow = &lds[yt * RPT * LSTR + x0];

    float acx0=0.f, acy0=0.f, acz0=0.f, acw0=0.f;
    float acx1=0.f, acy1=0.f, acz1=0.f, acw1=0.f;
    float acx2=0.f, acy2=0.f, acz2=0.f, acw2=0.f;
    float acx3=0.f, acy3=0.f, acz3=0.f, acw3=0.f;
    float r1,r2,r3,r4,r5,r6,r7,r8,r9,r10;

    LOAD_ROW(0); QROW0(0);
    LOAD_ROW(1); QROW1(0); QROW0(1);
    LOAD_ROW(2); QROW2(0); QROW1(1); QROW0(2);
    LOAD_ROW(3); QROW3(0); QROW2(1); QROW1(2); QROW0(3);
    LOAD_ROW(4); QROW4(0); QROW3(1); QROW2(2); QROW1(3);
    LOAD_ROW(5); QROW5(0); QROW4(1); QROW3(2); QROW2(3);
    LOAD_ROW(6); QROW6(0); QROW5(1); QROW4(2); QROW3(3);
    LOAD_ROW(7);           QROW6(1); QROW5(2); QROW4(3);
    LOAD_ROW(8);                     QROW6(2); QROW5(3);
    LOAD_ROW(9);                               QROW6(3);

    const int orow0 = y0 + yt * RPT;
    *reinterpret_cast<float4*>(op + (orow0 + 0) * HW + x0) = make_float4(acx0, acy0, acz0, acw0);
    *reinterpret_cast<float4*>(op + (orow0 + 1) * HW + x0) = make_float4(acx1, acy1, acz1, acw1);
    *reinterpret_cast<float4*>(op + (orow0 + 2) * HW + x0) = make_float4(acx2, acy2, acz2, acw2);
    *reinterpret_cast<float4*>(op + (orow0 + 3) * HW + x0) = make_float4(acx3, acy3, acz3, acw3);
}

extern "C" void kernel_launch(void* const* d_in, const int* in_sizes, int n_in,
                              void* d_out, int out_size, void* d_ws, size_t ws_size,
                              hipStream_t stream) {
    const float* x  = (const float*)d_in[0];   // (16,128,224,224) f32
    const float* kv = (const float*)d_in[1];   // (25,) f32
    float* out = (float*)d_out;
    dim3 grid(NB * CN * YTILES);               // 14336 blocks
    dwconv7x7_sym<<<grid, NTH, 0, stream>>>(x, kv, out);
}

// Round 4
// 275.459 us; speedup vs baseline: 4.6923x; 1.4559x over previous
//
#include <hip/hip_runtime.h>

#define CN 128
#define NB 16
#define KS 7
#define PD 3
#define HW 224
#define TILE_H 28       // 7 waves x 4 rows
#define ROWS_IN 34      // TILE_H + 6
#define LSTR 232        // 4 pad + 224 + 4 pad, floats
#define NTH 448         // 7 waves
#define NW 7
#define YTILES 8        // 224/28
#define RPT 4           // output rows per wave-lane

// weight i as a named scalar (uniform load -> s_load, lives in SGPR)
#define LW(i) const float w##i = kv[i];

// FMAs for output row Q with explicit weight scalars (no arrays anywhere).
// Window regs r1..r10 hold input cols x0-3 .. x0+6 of the current input row.
#define FMA_QROW(Q, W0,W1,W2,W3,W4,W5,W6) \
  acx##Q = fmaf(W0, r1,  acx##Q); \
  acx##Q = fmaf(W1, r2,  acx##Q); \
  acx##Q = fmaf(W2, r3,  acx##Q); \
  acx##Q = fmaf(W3, r4,  acx##Q); \
  acx##Q = fmaf(W4, r5,  acx##Q); \
  acx##Q = fmaf(W5, r6,  acx##Q); \
  acx##Q = fmaf(W6, r7,  acx##Q); \
  acy##Q = fmaf(W0, r2,  acy##Q); \
  acy##Q = fmaf(W1, r3,  acy##Q); \
  acy##Q = fmaf(W2, r4,  acy##Q); \
  acy##Q = fmaf(W3, r5,  acy##Q); \
  acy##Q = fmaf(W4, r6,  acy##Q); \
  acy##Q = fmaf(W5, r7,  acy##Q); \
  acy##Q = fmaf(W6, r8,  acy##Q); \
  acz##Q = fmaf(W0, r3,  acz##Q); \
  acz##Q = fmaf(W1, r4,  acz##Q); \
  acz##Q = fmaf(W2, r5,  acz##Q); \
  acz##Q = fmaf(W3, r6,  acz##Q); \
  acz##Q = fmaf(W4, r7,  acz##Q); \
  acz##Q = fmaf(W5, r8,  acz##Q); \
  acz##Q = fmaf(W6, r9,  acz##Q); \
  acw##Q = fmaf(W0, r4,  acw##Q); \
  acw##Q = fmaf(W1, r5,  acw##Q); \
  acw##Q = fmaf(W2, r6,  acw##Q); \
  acw##Q = fmaf(W3, r7,  acw##Q); \
  acw##Q = fmaf(W4, r8,  acw##Q); \
  acw##Q = fmaf(W5, r9,  acw##Q); \
  acw##Q = fmaf(W6, r10, acw##Q);

// Weight rows of the symmetric 7x7 (flat p -> param min(p,48-p)):
#define QROW0(Q) FMA_QROW(Q, w0,w1,w2,w3,w4,w5,w6)
#define QROW1(Q) FMA_QROW(Q, w7,w8,w9,w10,w11,w12,w13)
#define QROW2(Q) FMA_QROW(Q, w14,w15,w16,w17,w18,w19,w20)
#define QROW3(Q) FMA_QROW(Q, w21,w22,w23,w24,w23,w22,w21)
#define QROW4(Q) FMA_QROW(Q, w20,w19,w18,w17,w16,w15,w14)
#define QROW5(Q) FMA_QROW(Q, w13,w12,w11,w10,w9,w8,w7)
#define QROW6(Q) FMA_QROW(Q, w6,w5,w4,w3,w2,w1,w0)

// Load input row J of this wave's strip into named window regs.
#define LOAD_ROW(J) \
  { const float4 A_  = *reinterpret_cast<const float4*>(lrow + (J)*LSTR); \
    const float4 B_  = *reinterpret_cast<const float4*>(lrow + (J)*LSTR + 4); \
    const float4 C_  = *reinterpret_cast<const float4*>(lrow + (J)*LSTR + 8); \
    r1=A_.y; r2=A_.z; r3=A_.w; r4=B_.x; r5=B_.y; r6=B_.z; r7=B_.w; \
    r8=C_.x; r9=C_.y; r10=C_.z; }

__global__ __launch_bounds__(NTH, 4)   // VGPR budget 128 -> no spill
void dwconv7x7_sym(const float* __restrict__ x, const float* __restrict__ kv,
                   float* __restrict__ out) {
    __shared__ float lds[ROWS_IN * LSTR];
    const int bid   = blockIdx.x;
    const int plane = bid >> 3;                // /YTILES
    const int ytile = bid & 7;
    const int y0    = ytile * TILE_H;
    const float* xp = x + (size_t)plane * (HW * HW);
    float* op       = out + (size_t)plane * (HW * HW);

    const int tid  = threadIdx.x;
    const int wave = tid >> 6;
    const int lane = tid & 63;

    LW(0)  LW(1)  LW(2)  LW(3)  LW(4)  LW(5)  LW(6)  LW(7)  LW(8)  LW(9)
    LW(10) LW(11) LW(12) LW(13) LW(14) LW(15) LW(16) LW(17) LW(18) LW(19)
    LW(20) LW(21) LW(22) LW(23) LW(24)

    // Wave-aligned staging: wave w stages rows w, w+7, ...; lanes 0-55 carry
    // the 224-float payload (896 B contiguous load+store), lanes 56/57 zero
    // the 16 B side pads. All LDS writes are lane-consecutive 16 B.
    for (int r = wave; r < ROWS_IN; r += NW) {
        const int gr = y0 - PD + r;
        if (lane < 56) {
            float4 v = make_float4(0.f, 0.f, 0.f, 0.f);
            if (gr >= 0 && gr < HW)
                v = *reinterpret_cast<const float4*>(xp + gr * HW + lane * 4);
            *reinterpret_cast<float4*>(&lds[r * LSTR + 4 + lane * 4]) = v;
        } else if (lane == 56) {
            *reinterpret_cast<float4*>(&lds[r * LSTR]) =
                make_float4(0.f, 0.f, 0.f, 0.f);
        } else if (lane == 57) {
            *reinterpret_cast<float4*>(&lds[r * LSTR + 228]) =
                make_float4(0.f, 0.f, 0.f, 0.f);
        }
    }
    __syncthreads();

    if (lane < 56) {
        const int x0 = lane * 4;
        const float* lrow = &lds[wave * RPT * LSTR + x0];

        float acx0=0.f, acy0=0.f, acz0=0.f, acw0=0.f;
        float acx1=0.f, acy1=0.f, acz1=0.f, acw1=0.f;
        float acx2=0.f, acy2=0.f, acz2=0.f, acw2=0.f;
        float acx3=0.f, acy3=0.f, acz3=0.f, acw3=0.f;
        float r1,r2,r3,r4,r5,r6,r7,r8,r9,r10;

        LOAD_ROW(0); QROW0(0);
        LOAD_ROW(1); QROW1(0); QROW0(1);
        LOAD_ROW(2); QROW2(0); QROW1(1); QROW0(2);
        LOAD_ROW(3); QROW3(0); QROW2(1); QROW1(2); QROW0(3);
        LOAD_ROW(4); QROW4(0); QROW3(1); QROW2(2); QROW1(3);
        LOAD_ROW(5); QROW5(0); QROW4(1); QROW3(2); QROW2(3);
        LOAD_ROW(6); QROW6(0); QROW5(1); QROW4(2); QROW3(3);
        LOAD_ROW(7);           QROW6(1); QROW5(2); QROW4(3);
        LOAD_ROW(8);                     QROW6(2); QROW5(3);
        LOAD_ROW(9);                               QROW6(3);

        const int orow0 = y0 + wave * RPT;
        *reinterpret_cast<float4*>(op + (orow0 + 0) * HW + x0) = make_float4(acx0, acy0, acz0, acw0);
        *reinterpret_cast<float4*>(op + (orow0 + 1) * HW + x0) = make_float4(acx1, acy1, acz1, acw1);
        *reinterpret_cast<float4*>(op + (orow0 + 2) * HW + x0) = make_float4(acx2, acy2, acz2, acw2);
        *reinterpret_cast<float4*>(op + (orow0 + 3) * HW + x0) = make_float4(acx3, acy3, acz3, acw3);
    }
}

extern "C" void kernel_launch(void* const* d_in, const int* in_sizes, int n_in,
                              void* d_out, int out_size, void* d_ws, size_t ws_size,
                              hipStream_t stream) {
    const float* x  = (const float*)d_in[0];   // (16,128,224,224) f32
    const float* kv = (const float*)d_in[1];   // (25,) f32
    float* out = (float*)d_out;
    dim3 grid(NB * CN * YTILES);               // 16384 blocks
    dwconv7x7_sym<<<grid, NTH, 0, stream>>>(x, kv, out);
}